// Round 1
// baseline (768.928 us; speedup 1.0000x reference)
//
#include <hip/hip_runtime.h>
#include <hip/hip_bf16.h>
#include <cstdint>
#include <type_traits>

// ---------- types ----------
typedef __attribute__((ext_vector_type(8))) short short8v;          // MFMA A/B frag (8 bf16)
typedef __attribute__((ext_vector_type(8))) unsigned short ushort8v;
typedef __attribute__((ext_vector_type(4))) float f32x4;

__device__ __forceinline__ unsigned short f2bf(float f) {
    unsigned u = __builtin_bit_cast(unsigned, f);
    u = (u + 0x7fffu + ((u >> 16) & 1u)) >> 16;   // RNE
    return (unsigned short)u;
}
__device__ __forceinline__ float bf2f(unsigned short s) {
    return __builtin_bit_cast(float, ((unsigned)s) << 16);
}

// ---------- generic C = A @ W^T (+bias), A:f32 [M,K], W:f32|bf16 [N,K], C:f32|bf16 ----------
// 128x128 tile, BK=64, 4 waves, mfma_f32_16x16x32_bf16. All dims assumed %128==0 (K%64==0).
// blockIdx.z offsets: A += z*az (floats), W += z*wz (TW elems), C index += z*cz (elems).
template <typename TW, bool C_BF16>
__global__ __launch_bounds__(256) void gemm_awt(
    const float* __restrict__ A, int lda,
    const TW* __restrict__ W, int ldw,
    void* __restrict__ Cp, int ldc,
    const float* __restrict__ bias, int K,
    int az, int wz, size_t cz)
{
    __shared__ __attribute__((aligned(16))) unsigned short As[128 * 64];
    __shared__ __attribute__((aligned(16))) unsigned short Bs[128 * 64];

    A += (size_t)blockIdx.z * az;
    W += (size_t)blockIdx.z * wz;
    const size_t cbase = (size_t)blockIdx.z * cz;

    const int tid  = threadIdx.x;
    const int lane = tid & 63;
    const int wave = tid >> 6;
    const int wr = wave >> 1, wc = wave & 1;
    const size_t row0 = (size_t)blockIdx.y * 128;
    const size_t col0 = (size_t)blockIdx.x * 128;
    const int nk = K >> 6;

    f32x4 acc[4][4];
#pragma unroll
    for (int i = 0; i < 4; ++i)
#pragma unroll
        for (int j = 0; j < 4; ++j) acc[i][j] = f32x4{0.f, 0.f, 0.f, 0.f};

    float sa[4][8];
    float swf[4][8];
    ushort8v swb[4];

    auto load_tile = [&](int kt) {
#pragma unroll
        for (int it = 0; it < 4; ++it) {
            int g = tid + it * 256;
            int r = g >> 3, c8 = g & 7;
            const float4* ap = reinterpret_cast<const float4*>(A + (row0 + r) * (size_t)lda + kt * 64 + c8 * 8);
            float4 a0 = ap[0], a1 = ap[1];
            sa[it][0] = a0.x; sa[it][1] = a0.y; sa[it][2] = a0.z; sa[it][3] = a0.w;
            sa[it][4] = a1.x; sa[it][5] = a1.y; sa[it][6] = a1.z; sa[it][7] = a1.w;
            if constexpr (std::is_same<TW, float>::value) {
                const float4* wp = reinterpret_cast<const float4*>(W + (col0 + r) * (size_t)ldw + kt * 64 + c8 * 8);
                float4 w0 = wp[0], w1 = wp[1];
                swf[it][0] = w0.x; swf[it][1] = w0.y; swf[it][2] = w0.z; swf[it][3] = w0.w;
                swf[it][4] = w1.x; swf[it][5] = w1.y; swf[it][6] = w1.z; swf[it][7] = w1.w;
            } else {
                swb[it] = *reinterpret_cast<const ushort8v*>(W + (col0 + r) * (size_t)ldw + kt * 64 + c8 * 8);
            }
        }
    };
    auto write_tile = [&]() {
#pragma unroll
        for (int it = 0; it < 4; ++it) {
            int g = tid + it * 256;
            int r = g >> 3, c8 = g & 7;
            int idx = r * 64 + ((c8 ^ (r & 7)) << 3);   // XOR swizzle (T2)
            ushort8v av, wv;
#pragma unroll
            for (int j = 0; j < 8; ++j) av[j] = f2bf(sa[it][j]);
            *reinterpret_cast<ushort8v*>(&As[idx]) = av;
            if constexpr (std::is_same<TW, float>::value) {
#pragma unroll
                for (int j = 0; j < 8; ++j) wv[j] = f2bf(swf[it][j]);
            } else {
                wv = swb[it];
            }
            *reinterpret_cast<ushort8v*>(&Bs[idx]) = wv;
        }
    };

    load_tile(0);
    for (int kt = 0; kt < nk; ++kt) {
        __syncthreads();
        write_tile();
        __syncthreads();
        if (kt + 1 < nk) load_tile(kt + 1);   // prefetch overlaps MFMA below
#pragma unroll
        for (int kk = 0; kk < 2; ++kk) {
            short8v af[4], bfv[4];
#pragma unroll
            for (int mi = 0; mi < 4; ++mi) {
                int r = wr * 64 + mi * 16 + (lane & 15);
                int slot = kk * 4 + (lane >> 4);
                af[mi] = *reinterpret_cast<const short8v*>(&As[r * 64 + ((slot ^ (r & 7)) << 3)]);
            }
#pragma unroll
            for (int ni = 0; ni < 4; ++ni) {
                int r = wc * 64 + ni * 16 + (lane & 15);
                int slot = kk * 4 + (lane >> 4);
                bfv[ni] = *reinterpret_cast<const short8v*>(&Bs[r * 64 + ((slot ^ (r & 7)) << 3)]);
            }
#pragma unroll
            for (int mi = 0; mi < 4; ++mi)
#pragma unroll
                for (int ni = 0; ni < 4; ++ni)
                    acc[mi][ni] = __builtin_amdgcn_mfma_f32_16x16x32_bf16(af[mi], bfv[ni], acc[mi][ni], 0, 0, 0);
        }
    }

    // epilogue: C/D layout col=lane&15, row=(lane>>4)*4+reg  [verified m89/m91]
#pragma unroll
    for (int ni = 0; ni < 4; ++ni) {
        size_t col = col0 + wc * 64 + ni * 16 + (lane & 15);
        float bv = bias ? bias[col] : 0.0f;
#pragma unroll
        for (int mi = 0; mi < 4; ++mi) {
#pragma unroll
            for (int q = 0; q < 4; ++q) {
                size_t row = row0 + wr * 64 + mi * 16 + ((lane >> 4) << 2) + q;
                float v = acc[mi][ni][q] + bv;
                if constexpr (C_BF16)
                    ((unsigned short*)Cp)[cbase + row * (size_t)ldc + col] = f2bf(v);
                else
                    ((float*)Cp)[cbase + row * (size_t)ldc + col] = v;
            }
        }
    }
}

// ---------- 4x 512x512 f32 transpose ----------
__global__ void transpose4_512(const float* __restrict__ s0, float* __restrict__ d0,
                               const float* __restrict__ s1, float* __restrict__ d1,
                               const float* __restrict__ s2, float* __restrict__ d2,
                               const float* __restrict__ s3, float* __restrict__ d3)
{
    const float* src; float* dst;
    switch (blockIdx.z) {
        case 0: src = s0; dst = d0; break;
        case 1: src = s1; dst = d1; break;
        case 2: src = s2; dst = d2; break;
        default: src = s3; dst = d3; break;
    }
    __shared__ float t[32][33];
    int tx = threadIdx.x, ty = threadIdx.y;
    int bx = blockIdx.x * 32, by = blockIdx.y * 32;
#pragma unroll
    for (int j = 0; j < 4; ++j) t[ty + j * 8][tx] = src[(size_t)(by + ty + j * 8) * 512 + bx + tx];
    __syncthreads();
#pragma unroll
    for (int j = 0; j < 4; ++j) dst[(size_t)(bx + ty + j * 8) * 512 + by + tx] = t[tx][ty + j * 8];
}

// ---------- 4x bias combine: out[e] = W[e,:]·vin + vadd[e] ----------
struct BiasArgs {
    const float* W[4]; const float* vin[4]; const float* vadd[4]; float* out[4];
};
__global__ void bias_combine(BiasArgs a)
{
    int which = blockIdx.y;
    int e = blockIdx.x;
    int lane = threadIdx.x;   // 64
    const float* W = a.W[which] + (size_t)e * 512 + lane * 8;
    const float* v = a.vin[which] + lane * 8;
    float s = 0.f;
#pragma unroll
    for (int j = 0; j < 8; ++j) s += W[j] * v[j];
#pragma unroll
    for (int st = 1; st < 64; st <<= 1) s += __shfl_xor(s, st, 64);
    if (lane == 0) a.out[which][e] = s + a.vadd[which][e];
}

// ---------- logits[n,h] = 0.125 * <x[n,:], G[batch[n],h,:]> ----------
__global__ __launch_bounds__(256) void logits_kernel(
    const float* __restrict__ X, const unsigned short* __restrict__ G,
    const int* __restrict__ batch, float* __restrict__ logits)
{
    int n = blockIdx.x * 4 + (threadIdx.x >> 6);
    int lane = threadIdx.x & 63;
    int b = batch[n];
    const float4* xp = reinterpret_cast<const float4*>(X + (size_t)n * 512 + lane * 8);
    float4 x0 = xp[0], x1 = xp[1];
    float acc[8];
#pragma unroll
    for (int h = 0; h < 8; ++h) {
        ushort8v gv = *reinterpret_cast<const ushort8v*>(G + ((size_t)b * 8 + h) * 512 + lane * 8);
        acc[h] = x0.x * bf2f(gv[0]) + x0.y * bf2f(gv[1]) + x0.z * bf2f(gv[2]) + x0.w * bf2f(gv[3])
               + x1.x * bf2f(gv[4]) + x1.y * bf2f(gv[5]) + x1.z * bf2f(gv[6]) + x1.w * bf2f(gv[7]);
    }
#pragma unroll
    for (int h = 0; h < 8; ++h) {
#pragma unroll
        for (int st = 1; st < 64; st <<= 1) acc[h] += __shfl_xor(acc[h], st, 64);
    }
    float outv = 0.f;
#pragma unroll
    for (int h = 0; h < 8; ++h) if (lane == h) outv = acc[h];   // static indexing (rule #20)
    if (lane < 8) logits[(size_t)n * 8 + lane] = 0.125f * outv;
}

// ---------- segment softmax + weighted pool, one block per graph ----------
__global__ __launch_bounds__(256) void pool_kernel(
    const float* __restrict__ logits, const unsigned short* __restrict__ VV,
    const int* __restrict__ batch, float* __restrict__ pooled, int Nn)
{
    int b = blockIdx.x;
    int t = threadIdx.x;
    // segment bounds via binary search (batch sorted, every graph present)
    int lo = 0, hi = Nn;
    while (lo < hi) { int mid = (lo + hi) >> 1; if (batch[mid] < b) lo = mid + 1; else hi = mid; }
    const int s = lo;
    hi = Nn;
    while (lo < hi) { int mid = (lo + hi) >> 1; if (batch[mid] < b + 1) lo = mid + 1; else hi = mid; }
    const int e = lo;

    __shared__ float red[256];
    __shared__ float m_s[8], iz_s[8];
    __shared__ float w_s[256];

    const int h8 = t & 7, g = t >> 3;
    float lm = -1e30f;
    for (int n = s + g; n < e; n += 32) lm = fmaxf(lm, logits[(size_t)n * 8 + h8]);
    red[t] = lm; __syncthreads();
    for (int st = 128; st >= 8; st >>= 1) { if (t < st) red[t] = fmaxf(red[t], red[t + st]); __syncthreads(); }
    if (t < 8) m_s[t] = red[t];
    __syncthreads();
    float mh = m_s[h8];
    float ls = 0.f;
    for (int n = s + g; n < e; n += 32) ls += __expf(logits[(size_t)n * 8 + h8] - mh);
    red[t] = ls; __syncthreads();
    for (int st = 128; st >= 8; st >>= 1) { if (t < st) red[t] += red[t + st]; __syncthreads(); }
    if (t < 8) iz_s[t] = 1.0f / red[t];
    __syncthreads();

    float acc0 = 0.f, acc1 = 0.f;
    const int h1 = t >> 6, h2 = (t >> 6) + 4;
    for (int base = s; base < e; base += 32) {
        int nn = min(32, e - base);
        __syncthreads();
        if (t < nn * 8) {
            int nl = t >> 3, hh = t & 7;
            w_s[t] = __expf(logits[(size_t)(base + nl) * 8 + hh] - m_s[hh]) * iz_s[hh];
        }
        __syncthreads();
        for (int j = 0; j < nn; ++j) {
            float w1 = w_s[j * 8 + h1], w2 = w_s[j * 8 + h2];
            size_t off = (size_t)(base + j) * 512;
            acc0 += w1 * bf2f(VV[off + t]);
            acc1 += w2 * bf2f(VV[off + t + 256]);
        }
    }
    pooled[(size_t)b * 512 + t] = acc0;
    pooled[(size_t)b * 512 + t + 256] = acc1;
}

// ---------- LayerNorm over last dim (512) ----------
__global__ __launch_bounds__(256) void ln_kernel(
    const float* __restrict__ X, const float* __restrict__ gam,
    const float* __restrict__ bet, float* __restrict__ out)
{
    int r = blockIdx.x, t = threadIdx.x;
    float v0 = X[(size_t)r * 512 + t], v1 = X[(size_t)r * 512 + t + 256];
    __shared__ float red[256];
    red[t] = v0 + v1; __syncthreads();
    for (int st = 128; st >= 1; st >>= 1) { if (t < st) red[t] += red[t + st]; __syncthreads(); }
    float mean = red[0] * (1.0f / 512.0f);
    __syncthreads();
    red[t] = v0 * v0 + v1 * v1; __syncthreads();
    for (int st = 128; st >= 1; st >>= 1) { if (t < st) red[t] += red[t + st]; __syncthreads(); }
    float var = red[0] * (1.0f / 512.0f) - mean * mean;
    float rstd = rsqrtf(var + 1e-5f);
    out[(size_t)r * 512 + t]       = (v0 - mean) * rstd * gam[t] + bet[t];
    out[(size_t)r * 512 + t + 256] = (v1 - mean) * rstd * gam[t + 256] + bet[t + 256];
}

// ---------- launch ----------
extern "C" void kernel_launch(void* const* d_in, const int* in_sizes, int n_in,
                              void* d_out, int out_size, void* d_ws, size_t ws_size,
                              hipStream_t stream)
{
    const float* X   = (const float*)d_in[0];
    const float* SC  = (const float*)d_in[1];
    const float* Wq  = (const float*)d_in[2];
    const float* bq  = (const float*)d_in[3];
    const float* Wk  = (const float*)d_in[4];
    const float* bk  = (const float*)d_in[5];
    const float* Wv  = (const float*)d_in[6];
    const float* bv  = (const float*)d_in[7];
    const float* Wip = (const float*)d_in[8];
    const float* bip = (const float*)d_in[9];
    const float* Wmo = (const float*)d_in[10];
    const float* bmo = (const float*)d_in[11];
    const float* Wo  = (const float*)d_in[12];
    const float* bo  = (const float*)d_in[13];
    const float* lng = (const float*)d_in[14];
    const float* lnb = (const float*)d_in[15];
    const int*   batch = (const int*)d_in[16];

    const int Nn = in_sizes[0] / 512;   // 131072
    const int Bz = in_sizes[1] / 512;   // 4096

    const float* Wiq = Wip;
    const float* Wik = Wip + 512 * 512;
    const float* Wiv = Wip + 2 * 512 * 512;
    const float* biq = bip;
    const float* bik = bip + 512;
    const float* biv = bip + 1024;

    char* p = (char*)d_ws;
    auto alloc = [&](size_t bytes) -> char* {
        char* r = p; p += (bytes + 255) & ~(size_t)255; return r;
    };
    float* WkT  = (float*)alloc(512 * 512 * 4);
    float* WqT  = (float*)alloc(512 * 512 * 4);
    float* WvT  = (float*)alloc(512 * 512 * 4);
    float* WmoT = (float*)alloc(512 * 512 * 4);
    unsigned short* WkkT = (unsigned short*)alloc(512 * 512 * 2);   // (Wik@Wk)^T
    unsigned short* Wvv  = (unsigned short*)alloc(512 * 512 * 2);   // Wiv@Wv
    unsigned short* Wqq  = (unsigned short*)alloc(512 * 512 * 2);   // Wiq@Wq
    unsigned short* Wout = (unsigned short*)alloc(512 * 512 * 2);   // out_w@mha_out_w
    float* bkk = (float*)alloc(512 * 4);
    float* bqq = (float*)alloc(512 * 4);
    float* bvv = (float*)alloc(512 * 4);
    float* bou = (float*)alloc(512 * 4);
    float* QQ  = (float*)alloc((size_t)Bz * 512 * 4);
    unsigned short* G  = (unsigned short*)alloc((size_t)Bz * 8 * 512 * 2);
    unsigned short* VV = (unsigned short*)alloc((size_t)Nn * 512 * 2);
    float* logit  = (float*)alloc((size_t)Nn * 8 * 4);
    float* pooled = (float*)alloc((size_t)Bz * 512 * 4);
    float* out1   = (float*)alloc((size_t)Bz * 512 * 4);

    transpose4_512<<<dim3(16, 16, 4), dim3(32, 8), 0, stream>>>(Wk, WkT, Wq, WqT, Wv, WvT, Wmo, WmoT);

    BiasArgs ba;
    ba.W[0] = Wik; ba.vin[0] = bk;  ba.vadd[0] = bik; ba.out[0] = bkk;
    ba.W[1] = Wiq; ba.vin[1] = bq;  ba.vadd[1] = biq; ba.out[1] = bqq;
    ba.W[2] = Wiv; ba.vin[2] = bv;  ba.vadd[2] = biv; ba.out[2] = bvv;
    ba.W[3] = Wo;  ba.vin[3] = bmo; ba.vadd[3] = bo;  ba.out[3] = bou;
    bias_combine<<<dim3(512, 4), 64, 0, stream>>>(ba);

    // combined weights (bf16): WkkT = Wk^T@Wik^T, Wvv = Wiv@Wv, Wqq = Wiq@Wq, Wout = Wo@Wmo
    gemm_awt<float, true><<<dim3(4, 4), 256, 0, stream>>>(WkT, 512, Wik, 512, WkkT, 512, nullptr, 512, 0, 0, 0);
    gemm_awt<float, true><<<dim3(4, 4), 256, 0, stream>>>(Wiv, 512, WvT, 512, Wvv, 512, nullptr, 512, 0, 0, 0);
    gemm_awt<float, true><<<dim3(4, 4), 256, 0, stream>>>(Wiq, 512, WqT, 512, Wqq, 512, nullptr, 512, 0, 0, 0);
    gemm_awt<float, true><<<dim3(4, 4), 256, 0, stream>>>(Wo, 512, WmoT, 512, Wout, 512, nullptr, 512, 0, 0, 0);

    // QQ = scaffold @ Wqq^T + bqq   [B,512] f32
    gemm_awt<unsigned short, false><<<dim3(4, Bz / 128), 256, 0, stream>>>(SC, 512, Wqq, 512, QQ, 512, bqq, 512, 0, 0, 0);

    // G[b,h,:] = QQ[b,h*64:...]@WkkT[:,h*64:...]^T  -> [B,H,512] bf16 (z = head)
    gemm_awt<unsigned short, true><<<dim3(4, Bz / 128, 8), 256, 0, stream>>>(QQ, 512, WkkT, 512, G, 4096, nullptr, 64, 64, 64, 512);

    // VV = X @ Wvv^T + bvv  [N,512] bf16 — the one big GEMM
    gemm_awt<unsigned short, true><<<dim3(4, Nn / 128), 256, 0, stream>>>(X, 512, Wvv, 512, VV, 512, bvv, 512, 0, 0, 0);

    logits_kernel<<<Nn / 4, 256, 0, stream>>>(X, G, batch, logit);
    pool_kernel<<<Bz, 256, 0, stream>>>(logit, VV, batch, pooled, Nn);

    // out1 = pooled @ Wout^T + bout
    gemm_awt<unsigned short, false><<<dim3(4, Bz / 128), 256, 0, stream>>>(pooled, 512, Wout, 512, out1, 512, bou, 512, 0, 0, 0);

    ln_kernel<<<Bz, 256, 0, stream>>>(out1, lng, lnb, (float*)d_out);
}

// Round 2
// 612.967 us; speedup vs baseline: 1.2544x; 1.2544x over previous
//
#include <hip/hip_runtime.h>
#include <hip/hip_bf16.h>
#include <cstdint>
#include <type_traits>

typedef __attribute__((ext_vector_type(8))) short short8v;
typedef __attribute__((ext_vector_type(8))) unsigned short ushort8v;
typedef __attribute__((ext_vector_type(4))) float f32x4;

__device__ __forceinline__ unsigned short f2bf(float f) {
    unsigned u = __builtin_bit_cast(unsigned, f);
    u = (u + 0x7fffu + ((u >> 16) & 1u)) >> 16;
    return (unsigned short)u;
}
__device__ __forceinline__ float bf2f(unsigned short s) {
    return __builtin_bit_cast(float, ((unsigned)s) << 16);
}
__device__ __forceinline__ unsigned cvtpk(float lo, float hi) {
    unsigned r;
    asm("v_cvt_pk_bf16_f32 %0, %1, %2" : "=v"(r) : "v"(lo), "v"(hi));
    return r;
}

// ---------- GEMM core: C = A @ W^T (+bias). A:[M,K] f32|bf16, W:[N,K] f32|bf16, C:f32|bf16 ----------
// 128x128 tile, BK=64, 4 waves, mfma_f32_16x16x32_bf16. Dims %128 (K%64).
template <typename TA, typename TW, bool C_BF16>
__device__ __forceinline__ void gemm_core(
    const TA* __restrict__ A, int lda,
    const TW* __restrict__ W, int ldw,
    void* __restrict__ Cp, int ldc,
    const float* __restrict__ bias, int K, size_t cbase,
    int bx, int by, unsigned short* As, unsigned short* Bs)
{
    const int tid  = threadIdx.x;
    const int lane = tid & 63;
    const int wave = tid >> 6;
    const int wr = wave >> 1, wc = wave & 1;
    const size_t row0 = (size_t)by * 128;
    const size_t col0 = (size_t)bx * 128;
    const int nk = K >> 6;

    f32x4 acc[4][4];
#pragma unroll
    for (int i = 0; i < 4; ++i)
#pragma unroll
        for (int j = 0; j < 4; ++j) acc[i][j] = f32x4{0.f, 0.f, 0.f, 0.f};

    float saf[4][8]; ushort8v sab[4];
    float swf[4][8]; ushort8v swb[4];

    auto load_tile = [&](int kt) {
#pragma unroll
        for (int it = 0; it < 4; ++it) {
            int g = tid + it * 256;
            int r = g >> 3, c8 = g & 7;
            if constexpr (std::is_same<TA, float>::value) {
                const float4* ap = reinterpret_cast<const float4*>(A + (row0 + r) * (size_t)lda + kt * 64 + c8 * 8);
                float4 a0 = ap[0], a1 = ap[1];
                saf[it][0] = a0.x; saf[it][1] = a0.y; saf[it][2] = a0.z; saf[it][3] = a0.w;
                saf[it][4] = a1.x; saf[it][5] = a1.y; saf[it][6] = a1.z; saf[it][7] = a1.w;
            } else {
                sab[it] = *reinterpret_cast<const ushort8v*>(A + (row0 + r) * (size_t)lda + kt * 64 + c8 * 8);
            }
            if constexpr (std::is_same<TW, float>::value) {
                const float4* wp = reinterpret_cast<const float4*>(W + (col0 + r) * (size_t)ldw + kt * 64 + c8 * 8);
                float4 w0 = wp[0], w1 = wp[1];
                swf[it][0] = w0.x; swf[it][1] = w0.y; swf[it][2] = w0.z; swf[it][3] = w0.w;
                swf[it][4] = w1.x; swf[it][5] = w1.y; swf[it][6] = w1.z; swf[it][7] = w1.w;
            } else {
                swb[it] = *reinterpret_cast<const ushort8v*>(W + (col0 + r) * (size_t)ldw + kt * 64 + c8 * 8);
            }
        }
    };
    auto write_tile = [&]() {
#pragma unroll
        for (int it = 0; it < 4; ++it) {
            int g = tid + it * 256;
            int r = g >> 3, c8 = g & 7;
            int idx = r * 64 + ((c8 ^ (r & 7)) << 3);   // XOR swizzle (T2), same on read
            if constexpr (std::is_same<TA, float>::value) {
                uint4 av;
                av.x = cvtpk(saf[it][0], saf[it][1]); av.y = cvtpk(saf[it][2], saf[it][3]);
                av.z = cvtpk(saf[it][4], saf[it][5]); av.w = cvtpk(saf[it][6], saf[it][7]);
                *reinterpret_cast<uint4*>(&As[idx]) = av;
            } else {
                *reinterpret_cast<ushort8v*>(&As[idx]) = sab[it];
            }
            if constexpr (std::is_same<TW, float>::value) {
                uint4 wv;
                wv.x = cvtpk(swf[it][0], swf[it][1]); wv.y = cvtpk(swf[it][2], swf[it][3]);
                wv.z = cvtpk(swf[it][4], swf[it][5]); wv.w = cvtpk(swf[it][6], swf[it][7]);
                *reinterpret_cast<uint4*>(&Bs[idx]) = wv;
            } else {
                *reinterpret_cast<ushort8v*>(&Bs[idx]) = swb[it];
            }
        }
    };

    load_tile(0);
    for (int kt = 0; kt < nk; ++kt) {
        __syncthreads();
        write_tile();
        __syncthreads();
        if (kt + 1 < nk) load_tile(kt + 1);
#pragma unroll
        for (int kk = 0; kk < 2; ++kk) {
            short8v af[4], bfv[4];
#pragma unroll
            for (int mi = 0; mi < 4; ++mi) {
                int r = wr * 64 + mi * 16 + (lane & 15);
                int slot = kk * 4 + (lane >> 4);
                af[mi] = *reinterpret_cast<const short8v*>(&As[r * 64 + ((slot ^ (r & 7)) << 3)]);
            }
#pragma unroll
            for (int ni = 0; ni < 4; ++ni) {
                int r = wc * 64 + ni * 16 + (lane & 15);
                int slot = kk * 4 + (lane >> 4);
                bfv[ni] = *reinterpret_cast<const short8v*>(&Bs[r * 64 + ((slot ^ (r & 7)) << 3)]);
            }
#pragma unroll
            for (int mi = 0; mi < 4; ++mi)
#pragma unroll
                for (int ni = 0; ni < 4; ++ni)
                    acc[mi][ni] = __builtin_amdgcn_mfma_f32_16x16x32_bf16(af[mi], bfv[ni], acc[mi][ni], 0, 0, 0);
        }
    }

#pragma unroll
    for (int ni = 0; ni < 4; ++ni) {
        size_t col = col0 + wc * 64 + ni * 16 + (lane & 15);
        float bv = bias ? bias[col] : 0.0f;
#pragma unroll
        for (int mi = 0; mi < 4; ++mi) {
#pragma unroll
            for (int q = 0; q < 4; ++q) {
                size_t row = row0 + wr * 64 + mi * 16 + ((lane >> 4) << 2) + q;
                float v = acc[mi][ni][q] + bv;
                if constexpr (C_BF16)
                    ((unsigned short*)Cp)[cbase + row * (size_t)ldc + col] = f2bf(v);
                else
                    ((float*)Cp)[cbase + row * (size_t)ldc + col] = v;
            }
        }
    }
}

template <typename TA, typename TW, bool C_BF16>
__global__ __launch_bounds__(256) void gemm_awt(
    const TA* __restrict__ A, int lda, const TW* __restrict__ W, int ldw,
    void* __restrict__ Cp, int ldc, const float* __restrict__ bias, int K,
    int az, int wz, size_t cz)
{
    __shared__ __attribute__((aligned(16))) unsigned short As[128 * 64];
    __shared__ __attribute__((aligned(16))) unsigned short Bs[128 * 64];
    gemm_core<TA, TW, C_BF16>(A + (size_t)blockIdx.z * az, lda,
                              W + (size_t)blockIdx.z * wz, ldw,
                              Cp, ldc, bias, K, (size_t)blockIdx.z * cz,
                              blockIdx.x, blockIdx.y, As, Bs);
}

// 4 independent 512x512x512 f32xf32->bf16 weight GEMMs in one launch (z selects)
struct WG4 { const float* A[4]; const float* W[4]; unsigned short* C[4]; };
__global__ __launch_bounds__(256) void gemm_w4(WG4 a)
{
    __shared__ __attribute__((aligned(16))) unsigned short As[128 * 64];
    __shared__ __attribute__((aligned(16))) unsigned short Bs[128 * 64];
    int z = blockIdx.z;
    gemm_core<float, float, true>(a.A[z], 512, a.W[z], 512, a.C[z], 512,
                                  nullptr, 512, 0, blockIdx.x, blockIdx.y, As, Bs);
}

// ---------- 4x 512x512 f32 transpose ----------
__global__ void transpose4_512(const float* __restrict__ s0, float* __restrict__ d0,
                               const float* __restrict__ s1, float* __restrict__ d1,
                               const float* __restrict__ s2, float* __restrict__ d2,
                               const float* __restrict__ s3, float* __restrict__ d3)
{
    const float* src; float* dst;
    switch (blockIdx.z) {
        case 0: src = s0; dst = d0; break;
        case 1: src = s1; dst = d1; break;
        case 2: src = s2; dst = d2; break;
        default: src = s3; dst = d3; break;
    }
    __shared__ float t[32][33];
    int tx = threadIdx.x, ty = threadIdx.y;
    int bx = blockIdx.x * 32, by = blockIdx.y * 32;
#pragma unroll
    for (int j = 0; j < 4; ++j) t[ty + j * 8][tx] = src[(size_t)(by + ty + j * 8) * 512 + bx + tx];
    __syncthreads();
#pragma unroll
    for (int j = 0; j < 4; ++j) dst[(size_t)(bx + ty + j * 8) * 512 + by + tx] = t[tx][ty + j * 8];
}

// ---------- bias combines ----------
struct BiasArgs { const float* W[3]; const float* vin[3]; const float* vadd[3]; float* out[3]; };
__global__ void bias_combine3(BiasArgs a)
{
    int which = blockIdx.y, e = blockIdx.x, lane = threadIdx.x;
    const float* W = a.W[which] + (size_t)e * 512 + lane * 8;
    const float* v = a.vin[which] + lane * 8;
    float s = 0.f;
#pragma unroll
    for (int j = 0; j < 8; ++j) s += W[j] * v[j];
#pragma unroll
    for (int st = 1; st < 64; st <<= 1) s += __shfl_xor(s, st, 64);
    if (lane == 0) a.out[which][e] = s + a.vadd[which][e];
}
__global__ void bias_combine_bf(const unsigned short* __restrict__ W, const float* __restrict__ vin,
                                const float* __restrict__ vadd, float* __restrict__ out)
{
    int e = blockIdx.x, lane = threadIdx.x;
    ushort8v wv = *reinterpret_cast<const ushort8v*>(W + (size_t)e * 512 + lane * 8);
    const float* v = vin + lane * 8;
    float s = 0.f;
#pragma unroll
    for (int j = 0; j < 8; ++j) s += bf2f(wv[j]) * v[j];
#pragma unroll
    for (int st = 1; st < 64; st <<= 1) s += __shfl_xor(s, st, 64);
    if (lane == 0) out[e] = s + vadd[e];
}

// ---------- fused per-graph: logits (G-trick) + online softmax + weighted-X pooling ----------
// xw[b, h*512+k] = sum_n softmax_w[n,h] * X[n,k]   (bf16 out)
#define CHUNK 32
__global__ __launch_bounds__(256) void attn_pool(
    const float* __restrict__ X, const unsigned short* __restrict__ G,
    const int* __restrict__ batch, unsigned short* __restrict__ xw, int Nn)
{
    __shared__ __attribute__((aligned(16))) unsigned short Xs[CHUNK * 512];  // 32 KB bf16
    __shared__ __attribute__((aligned(16))) unsigned short Gs[8 * 512];      // 8 KB
    __shared__ float lg[CHUNK * 8];
    __shared__ float red[256];
    __shared__ float mh[8], Zh[8], sch[8];

    const int b = blockIdx.x, t = threadIdx.x;
    const int lane = t & 63, wvx = t >> 6;

    // segment bounds (batch sorted, every graph non-empty)
    int lo = 0, hi = Nn;
    while (lo < hi) { int mid = (lo + hi) >> 1; if (batch[mid] < b) lo = mid + 1; else hi = mid; }
    const int s = lo;
    hi = Nn;
    while (lo < hi) { int mid = (lo + hi) >> 1; if (batch[mid] < b + 1) lo = mid + 1; else hi = mid; }
    const int e = lo;

    if (t < 8) { mh[t] = -1e30f; Zh[t] = 0.f; }
    // G[b] -> LDS (8 KB = 512 uint4)
    {
        const uint4* gp = reinterpret_cast<const uint4*>(G + (size_t)b * 4096);
        reinterpret_cast<uint4*>(Gs)[t] = gp[t];
        reinterpret_cast<uint4*>(Gs)[t + 256] = gp[t + 256];
    }

    float acc[16];
#pragma unroll
    for (int i = 0; i < 16; ++i) acc[i] = 0.f;

    for (int base = s; base < e; base += CHUNK) {
        const int cnt = min(CHUNK, e - base);
        __syncthreads();   // protect Xs/lg from previous iteration's readers
        // stage X chunk -> bf16 LDS (thread writes uint4 at byte t*16: conflict-free)
#pragma unroll
        for (int i = 0; i < 8; ++i) {
            int u = t + 256 * i;            // uint4 index into Xs; bf16 flat = u*8
            int j = u >> 6;                 // row in chunk
            int col = (u & 63) * 8;
            uint4 w;
            if (j < cnt) {
                const float4* ap = reinterpret_cast<const float4*>(X + (size_t)(base + j) * 512 + col);
                float4 a0 = ap[0], a1 = ap[1];
                w.x = cvtpk(a0.x, a0.y); w.y = cvtpk(a0.z, a0.w);
                w.z = cvtpk(a1.x, a1.y); w.w = cvtpk(a1.z, a1.w);
            } else {
                w = uint4{0, 0, 0, 0};
            }
            *reinterpret_cast<uint4*>(&Xs[u * 8]) = w;
        }
        lg[t] = -1e30f;
        __syncthreads();
        // logits: wave per node; lane covers k = lane*8..+7 (16B LDS reads, conflict-free)
        for (int j = wvx; j < cnt; j += 4) {
            ushort8v xv = *reinterpret_cast<const ushort8v*>(&Xs[j * 512 + lane * 8]);
            float xf[8];
#pragma unroll
            for (int q = 0; q < 8; ++q) xf[q] = bf2f(xv[q]);
            float a8[8];
#pragma unroll
            for (int h = 0; h < 8; ++h) {
                ushort8v gv = *reinterpret_cast<const ushort8v*>(&Gs[h * 512 + lane * 8]);
                float sdot = 0.f;
#pragma unroll
                for (int q = 0; q < 8; ++q) sdot += xf[q] * bf2f(gv[q]);
                a8[h] = sdot;
            }
#pragma unroll
            for (int h = 0; h < 8; ++h)
#pragma unroll
                for (int st = 1; st < 64; st <<= 1) a8[h] += __shfl_xor(a8[h], st, 64);
            float ov = 0.f;
#pragma unroll
            for (int h = 0; h < 8; ++h) if (lane == h) ov = a8[h];
            if (lane < 8) lg[j * 8 + lane] = 0.125f * ov;
        }
        __syncthreads();
        // chunk max per head (t = j*8+h layout)
        red[t] = lg[t];
        __syncthreads();
        for (int st = 128; st >= 8; st >>= 1) { if (t < st) red[t] = fmaxf(red[t], red[t + st]); __syncthreads(); }
        if (t < 8) {
            float mnew = fmaxf(mh[t], red[t]);
            sch[t] = __expf(mh[t] - mnew);
            mh[t] = mnew;
        }
        __syncthreads();
        float pv = __expf(lg[t] - mh[t & 7]);
        lg[t] = pv;
        red[t] = pv;
        __syncthreads();
        for (int st = 128; st >= 8; st >>= 1) { if (t < st) red[t] += red[t + st]; __syncthreads(); }
        if (t < 8) Zh[t] = Zh[t] * sch[t] + red[t];
        // rescale + accumulate (sch synced by the tree barriers above)
        float sc[8];
#pragma unroll
        for (int h = 0; h < 8; ++h) sc[h] = sch[h];
#pragma unroll
        for (int i = 0; i < 16; ++i) acc[i] *= sc[i >> 1];
        for (int j = 0; j < cnt; ++j) {
            float x0 = bf2f(Xs[j * 512 + t]);
            float x1 = bf2f(Xs[j * 512 + t + 256]);
#pragma unroll
            for (int h = 0; h < 8; ++h) {
                float pj = lg[j * 8 + h];       // broadcast read
                acc[2 * h]     += pj * x0;
                acc[2 * h + 1] += pj * x1;
            }
        }
    }
    __syncthreads();
    // xw = acc / Z ; acc[i] holds flat = t + 256*i, h = i>>1
#pragma unroll
    for (int i = 0; i < 16; ++i) {
        float v = acc[i] / Zh[i >> 1];
        xw[(size_t)b * 4096 + t + 256 * i] = f2bf(v);
    }
}

// ---------- LayerNorm over last dim (512) ----------
__global__ __launch_bounds__(256) void ln_kernel(
    const float* __restrict__ X, const float* __restrict__ gam,
    const float* __restrict__ bet, float* __restrict__ out)
{
    int r = blockIdx.x, t = threadIdx.x;
    float v0 = X[(size_t)r * 512 + t], v1 = X[(size_t)r * 512 + t + 256];
    __shared__ float red[256];
    red[t] = v0 + v1; __syncthreads();
    for (int st = 128; st >= 1; st >>= 1) { if (t < st) red[t] += red[t + st]; __syncthreads(); }
    float mean = red[0] * (1.0f / 512.0f);
    __syncthreads();
    red[t] = v0 * v0 + v1 * v1; __syncthreads();
    for (int st = 128; st >= 1; st >>= 1) { if (t < st) red[t] += red[t + st]; __syncthreads(); }
    float var = red[0] * (1.0f / 512.0f) - mean * mean;
    float rstd = rsqrtf(var + 1e-5f);
    out[(size_t)r * 512 + t]       = (v0 - mean) * rstd * gam[t] + bet[t];
    out[(size_t)r * 512 + t + 256] = (v1 - mean) * rstd * gam[t + 256] + bet[t + 256];
}

// ---------- launch ----------
extern "C" void kernel_launch(void* const* d_in, const int* in_sizes, int n_in,
                              void* d_out, int out_size, void* d_ws, size_t ws_size,
                              hipStream_t stream)
{
    const float* X   = (const float*)d_in[0];
    const float* SC  = (const float*)d_in[1];
    const float* Wq  = (const float*)d_in[2];
    const float* bq  = (const float*)d_in[3];
    const float* Wk  = (const float*)d_in[4];
    const float* bk  = (const float*)d_in[5];
    const float* Wv  = (const float*)d_in[6];
    const float* bv  = (const float*)d_in[7];
    const float* Wip = (const float*)d_in[8];
    const float* bip = (const float*)d_in[9];
    const float* Wmo = (const float*)d_in[10];
    const float* bmo = (const float*)d_in[11];
    const float* Wo  = (const float*)d_in[12];
    const float* bo  = (const float*)d_in[13];
    const float* lng = (const float*)d_in[14];
    const float* lnb = (const float*)d_in[15];
    const int*   batch = (const int*)d_in[16];

    const int Nn = in_sizes[0] / 512;   // 131072
    const int Bz = in_sizes[1] / 512;   // 4096

    const float* Wiq = Wip;
    const float* Wik = Wip + 512 * 512;
    const float* Wiv = Wip + 2 * 512 * 512;
    const float* biq = bip;
    const float* bik = bip + 512;
    const float* biv = bip + 1024;
    (void)bik; // kk-bias contribution is softmax-shift-invariant -> exactly dropped

    char* p = (char*)d_ws;
    auto alloc = [&](size_t bytes) -> char* {
        char* r = p; p += (bytes + 255) & ~(size_t)255; return r;
    };
    float* WkT  = (float*)alloc(512 * 512 * 4);
    float* WqT  = (float*)alloc(512 * 512 * 4);
    float* WvT  = (float*)alloc(512 * 512 * 4);
    float* WmoT = (float*)alloc(512 * 512 * 4);
    unsigned short* Wqq   = (unsigned short*)alloc(512 * 512 * 2);  // Wiq@Wq
    unsigned short* WkkT  = (unsigned short*)alloc(512 * 512 * 2);  // (Wik@Wk)^T
    unsigned short* WvvT  = (unsigned short*)alloc(512 * 512 * 2);  // (Wiv@Wv)^T
    unsigned short* Woutc = (unsigned short*)alloc(512 * 512 * 2);  // out_w@mha_out_w
    unsigned short* Wbig  = (unsigned short*)alloc(512 * 4096 * 2); // [e][h*512+k]
    float* bqq   = (float*)alloc(512 * 4);
    float* bvv   = (float*)alloc(512 * 4);
    float* bou   = (float*)alloc(512 * 4);
    float* bias2 = (float*)alloc(512 * 4);
    float* QQ  = (float*)alloc((size_t)Bz * 512 * 4);
    unsigned short* G  = (unsigned short*)alloc((size_t)Bz * 8 * 512 * 2);
    unsigned short* xw = (unsigned short*)alloc((size_t)Bz * 4096 * 2);
    float* out1 = (float*)alloc((size_t)Bz * 512 * 4);

    // 1. transposes
    transpose4_512<<<dim3(16, 16, 4), dim3(32, 8), 0, stream>>>(Wk, WkT, Wq, WqT, Wv, WvT, Wmo, WmoT);

    // 2. bias folds: bqq = Wiq@bq+biq, bvv = Wiv@bv+biv, bou = Wo@bmo+bo
    BiasArgs ba;
    ba.W[0] = Wiq; ba.vin[0] = bq;  ba.vadd[0] = biq; ba.out[0] = bqq;
    ba.W[1] = Wiv; ba.vin[1] = bv;  ba.vadd[1] = biv; ba.out[1] = bvv;
    ba.W[2] = Wo;  ba.vin[2] = bmo; ba.vadd[2] = bo;  ba.out[2] = bou;
    bias_combine3<<<dim3(512, 3), 64, 0, stream>>>(ba);

    // 3. four 512^3 weight GEMMs, one launch
    WG4 wg;
    wg.A[0] = Wiq; wg.W[0] = WqT;  wg.C[0] = Wqq;    // Wqq  = Wiq@Wq
    wg.A[1] = WkT; wg.W[1] = Wik;  wg.C[1] = WkkT;   // WkkT = Wk^T@Wik^T
    wg.A[2] = WvT; wg.W[2] = Wiv;  wg.C[2] = WvvT;   // WvvT = Wv^T@Wiv^T
    wg.A[3] = Wo;  wg.W[3] = WmoT; wg.C[3] = Woutc;  // Woutc = Wo@Wmo
    gemm_w4<<<dim3(4, 4, 4), 256, 0, stream>>>(wg);

    // 4. bias2 = Woutc@bvv + bou
    bias_combine_bf<<<512, 64, 0, stream>>>(Woutc, bvv, bou, bias2);

    // 5. Wbig[e, h*512+k] = sum_d Woutc[e,h*64+d] * WvvT[k,h*64+d]
    gemm_awt<unsigned short, unsigned short, true><<<dim3(4, 4, 8), 256, 0, stream>>>(
        Woutc, 512, WvvT, 512, Wbig, 4096, nullptr, 64, 64, 64, 512);

    // 6. QQ = SC @ Wqq^T + bqq  (f32)
    gemm_awt<float, unsigned short, false><<<dim3(4, Bz / 128), 256, 0, stream>>>(
        SC, 512, Wqq, 512, QQ, 512, bqq, 512, 0, 0, 0);

    // 7. G[b,h,k] = sum_d QQ[b,h*64+d] * WkkT[k,h*64+d]  (bf16, [b][h][k])
    gemm_awt<float, unsigned short, true><<<dim3(4, Bz / 128, 8), 256, 0, stream>>>(
        QQ, 512, WkkT, 512, G, 4096, nullptr, 64, 64, 64, 512);

    // 8. fused logits + online softmax + weighted-X pooling -> xw (bf16)
    attn_pool<<<Bz, 256, 0, stream>>>(X, G, batch, xw, Nn);

    // 9. out1 = xw_flat @ Wbig^T + bias2  (M=Bz, K=4096, N=512)
    gemm_awt<unsigned short, unsigned short, false><<<dim3(4, Bz / 128), 256, 0, stream>>>(
        xw, 4096, Wbig, 4096, out1, 512, bias2, 4096, 0, 0, 0);

    // 10. LayerNorm
    ln_kernel<<<Bz, 256, 0, stream>>>(out1, lng, lnb, (float*)d_out);
}

// Round 3
// 564.448 us; speedup vs baseline: 1.3623x; 1.0860x over previous
//
#include <hip/hip_runtime.h>
#include <hip/hip_bf16.h>
#include <cstdint>
#include <type_traits>

typedef __attribute__((ext_vector_type(8))) short short8v;
typedef __attribute__((ext_vector_type(8))) unsigned short ushort8v;
typedef __attribute__((ext_vector_type(4))) float f32x4;

__device__ __forceinline__ unsigned short f2bf(float f) {
    unsigned u = __builtin_bit_cast(unsigned, f);
    u = (u + 0x7fffu + ((u >> 16) & 1u)) >> 16;
    return (unsigned short)u;
}
__device__ __forceinline__ float bf2f(unsigned short s) {
    return __builtin_bit_cast(float, ((unsigned)s) << 16);
}
__device__ __forceinline__ unsigned cvtpk(float lo, float hi) {
    unsigned r;
    asm("v_cvt_pk_bf16_f32 %0, %1, %2" : "=v"(r) : "v"(lo), "v"(hi));
    return r;
}

// ---------- GEMM core: C = A @ W^T (+bias). A:[M,K] f32|bf16, W:[N,K] f32|bf16, C:f32|bf16 ----------
template <typename TA, typename TW, bool C_BF16>
__device__ __forceinline__ void gemm_core(
    const TA* __restrict__ A, int lda,
    const TW* __restrict__ W, int ldw,
    void* __restrict__ Cp, int ldc,
    const float* __restrict__ bias, int K, size_t cbase,
    int bx, int by, unsigned short* As, unsigned short* Bs)
{
    const int tid  = threadIdx.x;
    const int lane = tid & 63;
    const int wave = tid >> 6;
    const int wr = wave >> 1, wc = wave & 1;
    const size_t row0 = (size_t)by * 128;
    const size_t col0 = (size_t)bx * 128;
    const int nk = K >> 6;

    f32x4 acc[4][4];
#pragma unroll
    for (int i = 0; i < 4; ++i)
#pragma unroll
        for (int j = 0; j < 4; ++j) acc[i][j] = f32x4{0.f, 0.f, 0.f, 0.f};

    float saf[4][8]; ushort8v sab[4];
    float swf[4][8]; ushort8v swb[4];

    auto load_tile = [&](int kt) {
#pragma unroll
        for (int it = 0; it < 4; ++it) {
            int g = tid + it * 256;
            int r = g >> 3, c8 = g & 7;
            if constexpr (std::is_same<TA, float>::value) {
                const float4* ap = reinterpret_cast<const float4*>(A + (row0 + r) * (size_t)lda + kt * 64 + c8 * 8);
                float4 a0 = ap[0], a1 = ap[1];
                saf[it][0] = a0.x; saf[it][1] = a0.y; saf[it][2] = a0.z; saf[it][3] = a0.w;
                saf[it][4] = a1.x; saf[it][5] = a1.y; saf[it][6] = a1.z; saf[it][7] = a1.w;
            } else {
                sab[it] = *reinterpret_cast<const ushort8v*>(A + (row0 + r) * (size_t)lda + kt * 64 + c8 * 8);
            }
            if constexpr (std::is_same<TW, float>::value) {
                const float4* wp = reinterpret_cast<const float4*>(W + (col0 + r) * (size_t)ldw + kt * 64 + c8 * 8);
                float4 w0 = wp[0], w1 = wp[1];
                swf[it][0] = w0.x; swf[it][1] = w0.y; swf[it][2] = w0.z; swf[it][3] = w0.w;
                swf[it][4] = w1.x; swf[it][5] = w1.y; swf[it][6] = w1.z; swf[it][7] = w1.w;
            } else {
                swb[it] = *reinterpret_cast<const ushort8v*>(W + (col0 + r) * (size_t)ldw + kt * 64 + c8 * 8);
            }
        }
    };
    auto write_tile = [&]() {
#pragma unroll
        for (int it = 0; it < 4; ++it) {
            int g = tid + it * 256;
            int r = g >> 3, c8 = g & 7;
            int idx = r * 64 + ((c8 ^ (r & 7)) << 3);   // XOR swizzle (T2), same on read
            if constexpr (std::is_same<TA, float>::value) {
                uint4 av;
                av.x = cvtpk(saf[it][0], saf[it][1]); av.y = cvtpk(saf[it][2], saf[it][3]);
                av.z = cvtpk(saf[it][4], saf[it][5]); av.w = cvtpk(saf[it][6], saf[it][7]);
                *reinterpret_cast<uint4*>(&As[idx]) = av;
            } else {
                *reinterpret_cast<ushort8v*>(&As[idx]) = sab[it];
            }
            if constexpr (std::is_same<TW, float>::value) {
                uint4 wv;
                wv.x = cvtpk(swf[it][0], swf[it][1]); wv.y = cvtpk(swf[it][2], swf[it][3]);
                wv.z = cvtpk(swf[it][4], swf[it][5]); wv.w = cvtpk(swf[it][6], swf[it][7]);
                *reinterpret_cast<uint4*>(&Bs[idx]) = wv;
            } else {
                *reinterpret_cast<ushort8v*>(&Bs[idx]) = swb[it];
            }
        }
    };

    load_tile(0);
    for (int kt = 0; kt < nk; ++kt) {
        __syncthreads();
        write_tile();
        __syncthreads();
        if (kt + 1 < nk) load_tile(kt + 1);
#pragma unroll
        for (int kk = 0; kk < 2; ++kk) {
            short8v af[4], bfv[4];
#pragma unroll
            for (int mi = 0; mi < 4; ++mi) {
                int r = wr * 64 + mi * 16 + (lane & 15);
                int slot = kk * 4 + (lane >> 4);
                af[mi] = *reinterpret_cast<const short8v*>(&As[r * 64 + ((slot ^ (r & 7)) << 3)]);
            }
#pragma unroll
            for (int ni = 0; ni < 4; ++ni) {
                int r = wc * 64 + ni * 16 + (lane & 15);
                int slot = kk * 4 + (lane >> 4);
                bfv[ni] = *reinterpret_cast<const short8v*>(&Bs[r * 64 + ((slot ^ (r & 7)) << 3)]);
            }
#pragma unroll
            for (int mi = 0; mi < 4; ++mi)
#pragma unroll
                for (int ni = 0; ni < 4; ++ni)
                    acc[mi][ni] = __builtin_amdgcn_mfma_f32_16x16x32_bf16(af[mi], bfv[ni], acc[mi][ni], 0, 0, 0);
        }
    }

#pragma unroll
    for (int ni = 0; ni < 4; ++ni) {
        size_t col = col0 + wc * 64 + ni * 16 + (lane & 15);
        float bv = bias ? bias[col] : 0.0f;
#pragma unroll
        for (int mi = 0; mi < 4; ++mi) {
#pragma unroll
            for (int q = 0; q < 4; ++q) {
                size_t row = row0 + wr * 64 + mi * 16 + ((lane >> 4) << 2) + q;
                float v = acc[mi][ni][q] + bv;
                if constexpr (C_BF16)
                    ((unsigned short*)Cp)[cbase + row * (size_t)ldc + col] = f2bf(v);
                else
                    ((float*)Cp)[cbase + row * (size_t)ldc + col] = v;
            }
        }
    }
}

template <typename TA, typename TW, bool C_BF16>
__global__ __launch_bounds__(256) void gemm_awt(
    const TA* __restrict__ A, int lda, const TW* __restrict__ W, int ldw,
    void* __restrict__ Cp, int ldc, const float* __restrict__ bias, int K,
    int az, int wz, size_t cz)
{
    __shared__ __attribute__((aligned(16))) unsigned short As[128 * 64];
    __shared__ __attribute__((aligned(16))) unsigned short Bs[128 * 64];
    gemm_core<TA, TW, C_BF16>(A + (size_t)blockIdx.z * az, lda,
                              W + (size_t)blockIdx.z * wz, ldw,
                              Cp, ldc, bias, K, (size_t)blockIdx.z * cz,
                              blockIdx.x, blockIdx.y, As, Bs);
}

// 4 independent 512x512x512 f32xf32->bf16 weight GEMMs in one launch (z selects)
struct WG4 { const float* A[4]; const float* W[4]; unsigned short* C[4]; };
__global__ __launch_bounds__(256) void gemm_w4(WG4 a)
{
    __shared__ __attribute__((aligned(16))) unsigned short As[128 * 64];
    __shared__ __attribute__((aligned(16))) unsigned short Bs[128 * 64];
    int z = blockIdx.z;
    gemm_core<float, float, true>(a.A[z], 512, a.W[z], 512, a.C[z], 512,
                                  nullptr, 512, 0, blockIdx.x, blockIdx.y, As, Bs);
}

// ---------- 4x 512x512 f32 transpose ----------
__global__ void transpose4_512(const float* __restrict__ s0, float* __restrict__ d0,
                               const float* __restrict__ s1, float* __restrict__ d1,
                               const float* __restrict__ s2, float* __restrict__ d2,
                               const float* __restrict__ s3, float* __restrict__ d3)
{
    const float* src; float* dst;
    switch (blockIdx.z) {
        case 0: src = s0; dst = d0; break;
        case 1: src = s1; dst = d1; break;
        case 2: src = s2; dst = d2; break;
        default: src = s3; dst = d3; break;
    }
    __shared__ float t[32][33];
    int tx = threadIdx.x, ty = threadIdx.y;
    int bx = blockIdx.x * 32, by = blockIdx.y * 32;
#pragma unroll
    for (int j = 0; j < 4; ++j) t[ty + j * 8][tx] = src[(size_t)(by + ty + j * 8) * 512 + bx + tx];
    __syncthreads();
#pragma unroll
    for (int j = 0; j < 4; ++j) dst[(size_t)(bx + ty + j * 8) * 512 + by + tx] = t[tx][ty + j * 8];
}

// ---------- bias combines ----------
struct BiasArgs { const float* W[3]; const float* vin[3]; const float* vadd[3]; float* out[3]; };
__global__ void bias_combine3(BiasArgs a)
{
    int which = blockIdx.y, e = blockIdx.x, lane = threadIdx.x;
    const float* W = a.W[which] + (size_t)e * 512 + lane * 8;
    const float* v = a.vin[which] + lane * 8;
    float s = 0.f;
#pragma unroll
    for (int j = 0; j < 8; ++j) s += W[j] * v[j];
#pragma unroll
    for (int st = 1; st < 64; st <<= 1) s += __shfl_xor(s, st, 64);
    if (lane == 0) a.out[which][e] = s + a.vadd[which][e];
}
__global__ void bias_combine_bf(const unsigned short* __restrict__ W, const float* __restrict__ vin,
                                const float* __restrict__ vadd, float* __restrict__ out)
{
    int e = blockIdx.x, lane = threadIdx.x;
    ushort8v wv = *reinterpret_cast<const ushort8v*>(W + (size_t)e * 512 + lane * 8);
    const float* v = vin + lane * 8;
    float s = 0.f;
#pragma unroll
    for (int j = 0; j < 8; ++j) s += bf2f(wv[j]) * v[j];
#pragma unroll
    for (int st = 1; st < 64; st <<= 1) s += __shfl_xor(s, st, 64);
    if (lane == 0) out[e] = s + vadd[e];
}

// ---------- segment bounds precompute: segs[b] = first node of graph b; segs[Bz] = Nn ----------
__global__ void seg_bounds(const int* __restrict__ batch, int* __restrict__ segs, int Nn, int Bz)
{
    int n = blockIdx.x * 256 + threadIdx.x;
    if (n >= Nn) return;
    int b0 = batch[n];
    int b1 = (n + 1 < Nn) ? batch[n + 1] : Bz;
    for (int b = b0 + 1; b <= b1; ++b) segs[b] = n + 1;
    if (n == 0) for (int b = 0; b <= b0; ++b) segs[b] = 0;
}

// ---------- fused attention pool, barrier-free wave-subgroup design ----------
// block = 1 graph (4 waves). wave handles heads {wid*2, wid*2+1}; 32-lane subgroup per head.
// lane owns dims kb*16..+15 (kb = lane&31). X read direct from global (L1 broadcast across
// subgroups/waves). Online softmax with defer-max (thr=8), shuffle-only reduction.
// xw[b, h*512+k] = sum_n softmax_w[n,h] * X[n,k]   (bf16)
__global__ __launch_bounds__(256, 4) void attn_pool_wave(
    const float* __restrict__ X, const unsigned short* __restrict__ G,
    const int* __restrict__ segs, unsigned short* __restrict__ xw)
{
    const int b    = blockIdx.x;
    const int wid  = threadIdx.x >> 6;
    const int lane = threadIdx.x & 63;
    const int h    = wid * 2 + (lane >> 5);   // head 0..7
    const int kb   = lane & 31;               // dim block
    const int s = segs[b], e = segs[b + 1];

    // G slice -> 16 f32 regs
    float g[16];
    {
        const ushort8v* gp = reinterpret_cast<const ushort8v*>(G + ((size_t)b * 8 + h) * 512 + kb * 16);
        ushort8v g0 = gp[0], g1 = gp[1];
#pragma unroll
        for (int q = 0; q < 8; ++q) { g[q] = bf2f(g0[q]); g[8 + q] = bf2f(g1[q]); }
    }

    float acc[16];
#pragma unroll
    for (int i = 0; i < 16; ++i) acc[i] = 0.f;
    float m = -1e30f, Z = 0.f;

    const float4* xr = reinterpret_cast<const float4*>(X + (size_t)s * 512 + kb * 16);
    float4 c0 = xr[0], c1 = xr[1], c2 = xr[2], c3 = xr[3];

    for (int j = s; j < e; ++j) {
        // prefetch next row slice (T14)
        int jn = (j + 1 < e) ? j + 1 : j;
        const float4* xn = reinterpret_cast<const float4*>(X + (size_t)jn * 512 + kb * 16);
        float4 n0 = xn[0], n1 = xn[1], n2 = xn[2], n3 = xn[3];

        // logit partial over this lane's 16 dims
        float p;
        p  = c0.x * g[0]  + c0.y * g[1]  + c0.z * g[2]  + c0.w * g[3];
        p += c1.x * g[4]  + c1.y * g[5]  + c1.z * g[6]  + c1.w * g[7];
        p += c2.x * g[8]  + c2.y * g[9]  + c2.z * g[10] + c2.w * g[11];
        p += c3.x * g[12] + c3.y * g[13] + c3.z * g[14] + c3.w * g[15];
        // reduce across the 32-lane subgroup (strides 1..16 stay within the half-wave)
#pragma unroll
        for (int st = 1; st < 32; st <<= 1) p += __shfl_xor(p, st, 64);
        p *= 0.125f;

        // online softmax, defer-max (rescale only when max grows by >8)
        if (p > m + 8.f) {
            float sc = __expf(m - p);
#pragma unroll
            for (int i = 0; i < 16; ++i) acc[i] *= sc;
            Z *= sc;
            m = p;
        }
        float w = __expf(p - m);
        Z += w;
        acc[0]  += w * c0.x; acc[1]  += w * c0.y; acc[2]  += w * c0.z; acc[3]  += w * c0.w;
        acc[4]  += w * c1.x; acc[5]  += w * c1.y; acc[6]  += w * c1.z; acc[7]  += w * c1.w;
        acc[8]  += w * c2.x; acc[9]  += w * c2.y; acc[10] += w * c2.z; acc[11] += w * c2.w;
        acc[12] += w * c3.x; acc[13] += w * c3.y; acc[14] += w * c3.z; acc[15] += w * c3.w;

        c0 = n0; c1 = n1; c2 = n2; c3 = n3;
    }

    float iz = 1.0f / Z;
    uint4 o0, o1;
    o0.x = cvtpk(acc[0] * iz, acc[1] * iz);   o0.y = cvtpk(acc[2] * iz, acc[3] * iz);
    o0.z = cvtpk(acc[4] * iz, acc[5] * iz);   o0.w = cvtpk(acc[6] * iz, acc[7] * iz);
    o1.x = cvtpk(acc[8] * iz, acc[9] * iz);   o1.y = cvtpk(acc[10] * iz, acc[11] * iz);
    o1.z = cvtpk(acc[12] * iz, acc[13] * iz); o1.w = cvtpk(acc[14] * iz, acc[15] * iz);
    unsigned short* op = xw + (size_t)b * 4096 + h * 512 + kb * 16;
    reinterpret_cast<uint4*>(op)[0] = o0;
    reinterpret_cast<uint4*>(op)[1] = o1;
}

// ---------- LayerNorm with 4-way K-split partial reduce + bias ----------
__global__ __launch_bounds__(256) void ln4_kernel(
    const float* __restrict__ parts, int Bz, const float* __restrict__ bias2,
    const float* __restrict__ gam, const float* __restrict__ bet, float* __restrict__ out)
{
    int r = blockIdx.x, t = threadIdx.x;
    size_t M = (size_t)Bz * 512;
    float v0 = bias2[t], v1 = bias2[t + 256];
#pragma unroll
    for (int z = 0; z < 4; ++z) {
        v0 += parts[z * M + (size_t)r * 512 + t];
        v1 += parts[z * M + (size_t)r * 512 + t + 256];
    }
    __shared__ float red[256];
    red[t] = v0 + v1; __syncthreads();
    for (int st = 128; st >= 1; st >>= 1) { if (t < st) red[t] += red[t + st]; __syncthreads(); }
    float mean = red[0] * (1.0f / 512.0f);
    __syncthreads();
    red[t] = v0 * v0 + v1 * v1; __syncthreads();
    for (int st = 128; st >= 1; st >>= 1) { if (t < st) red[t] += red[t + st]; __syncthreads(); }
    float var = red[0] * (1.0f / 512.0f) - mean * mean;
    float rstd = rsqrtf(var + 1e-5f);
    out[(size_t)r * 512 + t]       = (v0 - mean) * rstd * gam[t] + bet[t];
    out[(size_t)r * 512 + t + 256] = (v1 - mean) * rstd * gam[t + 256] + bet[t + 256];
}

// ---------- launch ----------
extern "C" void kernel_launch(void* const* d_in, const int* in_sizes, int n_in,
                              void* d_out, int out_size, void* d_ws, size_t ws_size,
                              hipStream_t stream)
{
    const float* X   = (const float*)d_in[0];
    const float* SC  = (const float*)d_in[1];
    const float* Wq  = (const float*)d_in[2];
    const float* bq  = (const float*)d_in[3];
    const float* Wk  = (const float*)d_in[4];
    const float* bk  = (const float*)d_in[5];
    const float* Wv  = (const float*)d_in[6];
    const float* bv  = (const float*)d_in[7];
    const float* Wip = (const float*)d_in[8];
    const float* bip = (const float*)d_in[9];
    const float* Wmo = (const float*)d_in[10];
    const float* bmo = (const float*)d_in[11];
    const float* Wo  = (const float*)d_in[12];
    const float* bo  = (const float*)d_in[13];
    const float* lng = (const float*)d_in[14];
    const float* lnb = (const float*)d_in[15];
    const int*   batch = (const int*)d_in[16];

    const int Nn = in_sizes[0] / 512;   // 131072
    const int Bz = in_sizes[1] / 512;   // 4096

    const float* Wiq = Wip;
    const float* Wik = Wip + 512 * 512;
    const float* Wiv = Wip + 2 * 512 * 512;
    const float* biq = bip;
    const float* biv = bip + 1024;
    // bik dropped exactly: softmax shift-invariance (per-graph constant logit offset)

    char* p = (char*)d_ws;
    auto alloc = [&](size_t bytes) -> char* {
        char* r = p; p += (bytes + 255) & ~(size_t)255; return r;
    };
    float* WkT  = (float*)alloc(512 * 512 * 4);
    float* WqT  = (float*)alloc(512 * 512 * 4);
    float* WvT  = (float*)alloc(512 * 512 * 4);
    float* WmoT = (float*)alloc(512 * 512 * 4);
    unsigned short* Wqq   = (unsigned short*)alloc(512 * 512 * 2);  // Wiq@Wq
    unsigned short* WkkT  = (unsigned short*)alloc(512 * 512 * 2);  // (Wik@Wk)^T
    unsigned short* WvvT  = (unsigned short*)alloc(512 * 512 * 2);  // (Wiv@Wv)^T
    unsigned short* Woutc = (unsigned short*)alloc(512 * 512 * 2);  // out_w@mha_out_w
    unsigned short* Wbig  = (unsigned short*)alloc(512 * 4096 * 2); // [e][h*512+k]
    float* bqq   = (float*)alloc(512 * 4);
    float* bvv   = (float*)alloc(512 * 4);
    float* bou   = (float*)alloc(512 * 4);
    float* bias2 = (float*)alloc(512 * 4);
    float* QQ  = (float*)alloc((size_t)Bz * 512 * 4);
    unsigned short* G  = (unsigned short*)alloc((size_t)Bz * 8 * 512 * 2);  // 33.5 MB
    unsigned short* xw = (unsigned short*)alloc((size_t)Bz * 4096 * 2);
    int* segs = (int*)alloc((size_t)(Bz + 1) * 4);
    // out1 K-split partials (4 x [Bz,512] f32 = 32 MB) ALIAS G: G's lifetime ends
    // when attn_pool_wave completes, before the out1 GEMM runs.
    float* parts = (float*)G;

    // 1. transposes
    transpose4_512<<<dim3(16, 16, 4), dim3(32, 8), 0, stream>>>(Wk, WkT, Wq, WqT, Wv, WvT, Wmo, WmoT);

    // 2. bias folds: bqq = Wiq@bq+biq, bvv = Wiv@bv+biv, bou = Wo@bmo+bo
    BiasArgs ba;
    ba.W[0] = Wiq; ba.vin[0] = bq;  ba.vadd[0] = biq; ba.out[0] = bqq;
    ba.W[1] = Wiv; ba.vin[1] = bv;  ba.vadd[1] = biv; ba.out[1] = bvv;
    ba.W[2] = Wo;  ba.vin[2] = bmo; ba.vadd[2] = bo;  ba.out[2] = bou;
    bias_combine3<<<dim3(512, 3), 64, 0, stream>>>(ba);

    // 2b. segment bounds
    seg_bounds<<<(Nn + 255) / 256, 256, 0, stream>>>(batch, segs, Nn, Bz);

    // 3. four 512^3 weight GEMMs, one launch
    WG4 wg;
    wg.A[0] = Wiq; wg.W[0] = WqT;  wg.C[0] = Wqq;    // Wqq  = Wiq@Wq
    wg.A[1] = WkT; wg.W[1] = Wik;  wg.C[1] = WkkT;   // WkkT = Wk^T@Wik^T
    wg.A[2] = WvT; wg.W[2] = Wiv;  wg.C[2] = WvvT;   // WvvT = Wv^T@Wiv^T
    wg.A[3] = Wo;  wg.W[3] = WmoT; wg.C[3] = Woutc;  // Woutc = Wo@Wmo
    gemm_w4<<<dim3(4, 4, 4), 256, 0, stream>>>(wg);

    // 4. bias2 = Woutc@bvv + bou
    bias_combine_bf<<<512, 64, 0, stream>>>(Woutc, bvv, bou, bias2);

    // 5. Wbig[e, h*512+k] = sum_d Woutc[e,h*64+d] * WvvT[k,h*64+d]
    gemm_awt<unsigned short, unsigned short, true><<<dim3(4, 4, 8), 256, 0, stream>>>(
        Woutc, 512, WvvT, 512, Wbig, 4096, nullptr, 64, 64, 64, 512);

    // 6. QQ = SC @ Wqq^T + bqq  (f32)
    gemm_awt<float, unsigned short, false><<<dim3(4, Bz / 128), 256, 0, stream>>>(
        SC, 512, Wqq, 512, QQ, 512, bqq, 512, 0, 0, 0);

    // 7. G[b,h,k] = sum_d QQ[b,h*64+d] * WkkT[k,h*64+d]  (bf16, [b][h][k])
    gemm_awt<float, unsigned short, true><<<dim3(4, Bz / 128, 8), 256, 0, stream>>>(
        QQ, 512, WkkT, 512, G, 4096, nullptr, 64, 64, 64, 512);

    // 8. fused logits + online softmax + weighted-X pooling -> xw (bf16)
    attn_pool_wave<<<Bz, 256, 0, stream>>>(X, G, segs, xw);

    // 9. out1 partials: K-split x4 of xw_flat @ Wbig^T  (M=Bz, K=4096, N=512)
    gemm_awt<unsigned short, unsigned short, false><<<dim3(4, Bz / 128, 4), 256, 0, stream>>>(
        xw, 4096, Wbig, 4096, parts, 512, nullptr, 1024, 1024, 1024, (size_t)Bz * 512);

    // 10. reduce partials + bias2 + LayerNorm
    ln4_kernel<<<Bz, 256, 0, stream>>>(parts, Bz, bias2, lng, lnb, (float*)d_out);
}